// Round 3
// baseline (1083.758 us; speedup 1.0000x reference)
//
#include <hip/hip_runtime.h>
#include <cstddef>
#include <cstdint>

// R5: occupancy + amplification + launch-count attack.
//  - gemm_adj (z2/g3): BM=128xNT=128, 2x2 wave grid, single-buffer 32 KB LDS
//    -> all 632 blocks co-resident (no tail), B LDS-read amp 4x->2x,
//    B L2 re-stage traffic halved, 2x MFMA per staged byte.
//  - midchain: ONE kernel for reduce_g1 -> z1=tanh(g1@w3) -> t2=z1@w4 ->
//    t2t bf16 transpose (w3/w4/z1 LDS-resident, f32-exact).
//  - reduce128h: reduce partials -> g3(f32)+g3b(bf16) AND h=g3@Mm -> hb(bf16)
//    (Mm precomputed first); zero-pad rows fused. 15 -> 10 dispatches.
//
// Math (exact-equivalent restructure of reference):
//   g1=adj@z0; z1=tanh(g1@w3); t2=z1@w4; z2=tanh(adj@t2); g3=adj@z2;
//   zhat=g3@w5 -> out0; Mm=w5@w5^T; h=g3@Mm; out1=sigmoid(h@g3^T) -> out1

typedef __attribute__((ext_vector_type(8))) short bf16x8;
typedef __attribute__((ext_vector_type(4))) float f32x4;

#define NROWS 10000
#define MP    10048   // col (K) padding, multiple of 64
#define MPAD  10112   // row padding = 79*128

__device__ inline unsigned short f2bf(float f) {
  union { float f; unsigned int u; } a; a.f = f;
  unsigned int u = a.u;
  u += 0x7fffu + ((u >> 16) & 1u);  // round-to-nearest-even
  return (unsigned short)(u >> 16);
}

__device__ inline void gl_lds16(const void* g, void* l) {
  __builtin_amdgcn_global_load_lds(
      (const __attribute__((address_space(1))) void*)g,
      (__attribute__((address_space(3))) void*)l, 16, 0, 0);
}

// ---------------------------------------------------------------------------
// GEMM1 fused with adj f32->bf16 conversion. Tile 64x32, BK=64, split-K.
// Writes adjb bf16 [MPAD][MP] (zero-padded) as side product; P partials 32-wide.
// ---------------------------------------------------------------------------
__global__ __launch_bounds__(256)
void gemm1_fused(const float* __restrict__ adj, const short* __restrict__ zt,
                 short* __restrict__ adjb, float* __restrict__ P,
                 int kChunks, int S) {
  __shared__ short As[64 * 64];
  __shared__ short Bs[32 * 64];
  const int tid  = threadIdx.x;
  const int wave = tid >> 6;
  const int lane = tid & 63;
  const int row0 = blockIdx.y * 64;
  const int s    = blockIdx.z;
  const int t0 = (int)((long long)s * kChunks / S);
  const int t1 = (int)((long long)(s + 1) * kChunks / S);

  f32x4 acc[2];
#pragma unroll
  for (int i = 0; i < 2; ++i) acc[i] = (f32x4){0.f, 0.f, 0.f, 0.f};

  const int lr = lane >> 3;
  const int lk = ((lane & 7) ^ lr) * 8;   // swizzled source granule for B
  const int fr = lane & 15, fq = lane >> 4, sw = lane & 7;

  const int ar  = tid >> 2;      // A-stage row 0..63
  const int acq = tid & 3;       // col quarter (16 f32)
  const int gr  = row0 + ar;
  const bool rv = gr < NROWS;

  for (int t = t0; t < t1; ++t) {
    const int k0 = t * 64;
    __syncthreads();
    gl_lds16(zt + (size_t)(8 * wave + lr) * MP + k0 + lk, (void*)(Bs + wave * 512));
    const int gc = k0 + acq * 16;
    float4 f[4];
#pragma unroll
    for (int j = 0; j < 4; ++j) {
      int c = gc + 4 * j;
      f[j] = (rv && c < NROWS) ? *(const float4*)(adj + (size_t)gr * NROWS + c)
                               : make_float4(0.f, 0.f, 0.f, 0.f);
    }
    unsigned short h[16] __attribute__((aligned(16)));
#pragma unroll
    for (int j = 0; j < 4; ++j) {
      h[4 * j + 0] = f2bf(f[j].x); h[4 * j + 1] = f2bf(f[j].y);
      h[4 * j + 2] = f2bf(f[j].z); h[4 * j + 3] = f2bf(f[j].w);
    }
    *(uint4*)(adjb + (size_t)gr * MP + gc)     = *(const uint4*)&h[0];
    *(uint4*)(adjb + (size_t)gr * MP + gc + 8) = *(const uint4*)&h[8];
    *(bf16x8*)&As[ar * 64 + ((acq * 2 + 0) ^ (ar & 7)) * 8] = *(const bf16x8*)&h[0];
    *(bf16x8*)&As[ar * 64 + ((acq * 2 + 1) ^ (ar & 7)) * 8] = *(const bf16x8*)&h[8];
    __syncthreads();
#pragma unroll
    for (int ks = 0; ks < 2; ++ks) {
      const int go = ((ks * 4 + fq) ^ sw) * 8;
      bf16x8 af = *(const bf16x8*)&As[(wave * 16 + fr) * 64 + go];
#pragma unroll
      for (int nt = 0; nt < 2; ++nt) {
        bf16x8 bfr = *(const bf16x8*)&Bs[(nt * 16 + fr) * 64 + go];
        acc[nt] = __builtin_amdgcn_mfma_f32_16x16x32_bf16(af, bfr, acc[nt], 0, 0, 0);
      }
    }
  }
  float* Cs = P + (size_t)s * MPAD * 32;
  const int rbase = row0 + wave * 16 + (lane >> 4) * 4;
  const int cbase = lane & 15;
#pragma unroll
  for (int nt = 0; nt < 2; ++nt) {
    const int cc = cbase + nt * 16;
#pragma unroll
    for (int r = 0; r < 4; ++r)
      Cs[(size_t)(rbase + r) * 32 + cc] = acc[nt][r];
  }
}

// ---------------------------------------------------------------------------
// adj GEMM: P[s] += A[128-row tile] @ Bt^T.  BM=128, NT=128, BK=64.
// Single-buffered 32 KB LDS -> ~4 blocks/CU, all 632 blocks co-resident.
// 2x2 wave grid: each wave owns a 64x64 output quadrant (acc 4x4 frags).
// ---------------------------------------------------------------------------
__global__ __launch_bounds__(256)
void gemm_adj(const short* __restrict__ A, const short* __restrict__ Bt,
              float* __restrict__ P, int kChunks, int S) {
  __shared__ short As[128 * 64];
  __shared__ short Bs[128 * 64];
  const int tid  = threadIdx.x;
  const int wave = tid >> 6;
  const int lane = tid & 63;
  const int row0 = blockIdx.y * 128;
  const int s    = blockIdx.z;
  const int t0 = (int)((long long)s * kChunks / S);
  const int t1 = (int)((long long)(s + 1) * kChunks / S);
  const int wr = wave >> 1, wc = wave & 1;

  f32x4 acc[4][4];
#pragma unroll
  for (int m = 0; m < 4; ++m)
#pragma unroll
    for (int n = 0; n < 4; ++n) acc[m][n] = (f32x4){0.f, 0.f, 0.f, 0.f};

  const int lr = lane >> 3;
  const int lk = ((lane & 7) ^ lr) * 8;
  const int fr = lane & 15, fq = lane >> 4, sw = lane & 7;

  for (int t = t0; t < t1; ++t) {
    const int k0 = t * 64;
    __syncthreads();              // prior compute done before overwrite
#pragma unroll
    for (int i = 0; i < 4; ++i) {
      int c = wave + 4 * i;
      gl_lds16(A + (size_t)(row0 + 8 * c + lr) * MP + k0 + lk, (void*)(As + c * 512));
      gl_lds16(Bt + (size_t)(8 * c + lr) * MP + k0 + lk, (void*)(Bs + c * 512));
    }
    __syncthreads();              // drains gl_lds16 (vmcnt0)
#pragma unroll
    for (int ks = 0; ks < 2; ++ks) {
      const int go = ((ks * 4 + fq) ^ sw) * 8;
      bf16x8 av[4], bv[4];
#pragma unroll
      for (int m = 0; m < 4; ++m)
        av[m] = *(const bf16x8*)&As[(wr * 64 + m * 16 + fr) * 64 + go];
#pragma unroll
      for (int n = 0; n < 4; ++n)
        bv[n] = *(const bf16x8*)&Bs[(wc * 64 + n * 16 + fr) * 64 + go];
#pragma unroll
      for (int m = 0; m < 4; ++m)
#pragma unroll
        for (int n = 0; n < 4; ++n)
          acc[m][n] = __builtin_amdgcn_mfma_f32_16x16x32_bf16(av[m], bv[n], acc[m][n], 0, 0, 0);
    }
  }

  float* Cs = P + (size_t)s * MPAD * 128;
  const int q = lane >> 4;
#pragma unroll
  for (int m = 0; m < 4; ++m) {
    const int rb = row0 + wr * 64 + m * 16 + q * 4;
#pragma unroll
    for (int n = 0; n < 4; ++n) {
      const int cc = wc * 64 + n * 16 + fr;
#pragma unroll
      for (int r = 0; r < 4; ++r)
        Cs[(size_t)(rb + r) * 128 + cc] = acc[m][n][r];
    }
  }
}

// ---------------------------------------------------------------------------
// Recon GEMM: out1 = sigmoid(hb @ g3b^T), 128x128 tile, K=128.
// ---------------------------------------------------------------------------
__global__ __launch_bounds__(256)
void gemm_recon(const short* __restrict__ A, const short* __restrict__ Bt,
                float* __restrict__ C) {
  __shared__ short As[128 * 64];
  __shared__ short Bs[128 * 64];
  const int tid  = threadIdx.x;
  const int wave = tid >> 6;
  const int lane = tid & 63;
  const int row0 = blockIdx.y * 128;
  const int col0 = blockIdx.x * 128;

  f32x4 acc[2][8];
#pragma unroll
  for (int i = 0; i < 2; ++i)
#pragma unroll
    for (int j = 0; j < 8; ++j) acc[i][j] = (f32x4){0.f, 0.f, 0.f, 0.f};

  const int lr = lane >> 3;
  const int lk = ((lane & 7) ^ lr) * 8;
  const int fr = lane & 15, fq = lane >> 4, sw = lane & 7;

  for (int t = 0; t < 2; ++t) {
    const int k0 = t * 64;
    __syncthreads();
#pragma unroll
    for (int i = 0; i < 4; ++i) {
      int c = wave + 4 * i;
      gl_lds16(A + (size_t)(row0 + 8 * c + lr) * 128 + k0 + lk, (void*)(As + c * 512));
      gl_lds16(Bt + (size_t)(col0 + 8 * c + lr) * 128 + k0 + lk, (void*)(Bs + c * 512));
    }
    __syncthreads();
#pragma unroll
    for (int ks = 0; ks < 2; ++ks) {
      const int go = ((ks * 4 + fq) ^ sw) * 8;
      bf16x8 a0 = *(const bf16x8*)&As[(wave * 32 + fr) * 64 + go];
      bf16x8 a1 = *(const bf16x8*)&As[(wave * 32 + 16 + fr) * 64 + go];
#pragma unroll
      for (int nt = 0; nt < 8; ++nt) {
        bf16x8 bfr = *(const bf16x8*)&Bs[(nt * 16 + fr) * 64 + go];
        acc[0][nt] = __builtin_amdgcn_mfma_f32_16x16x32_bf16(a0, bfr, acc[0][nt], 0, 0, 0);
        acc[1][nt] = __builtin_amdgcn_mfma_f32_16x16x32_bf16(a1, bfr, acc[1][nt], 0, 0, 0);
      }
    }
  }

  const int q = lane >> 4;
#pragma unroll
  for (int mf = 0; mf < 2; ++mf) {
    const int rb = row0 + wave * 32 + mf * 16 + q * 4;
#pragma unroll
    for (int nt = 0; nt < 8; ++nt) {
      const int cc = col0 + nt * 16 + (lane & 15);
      if (cc >= NROWS) continue;
#pragma unroll
      for (int r = 0; r < 4; ++r) {
        const int rr = rb + r;
        if (rr < NROWS) {
          float v = acc[mf][nt][r];
          v = 1.0f / (1.0f + __expf(-v));
          C[(size_t)rr * NROWS + cc] = v;
        }
      }
    }
  }
}

// ---------------------------------------------------------------------------
// Middle chain, one kernel per 64 rows:
//   g1 = sum(P partials); z1 = tanh(g1@w3); t2 = z1@w4; t2t = bf16(t2)^T
// All f32 VALU (exact), weights LDS-resident.
// ---------------------------------------------------------------------------
__global__ __launch_bounds__(256)
void midchain(const float* __restrict__ P, const float* __restrict__ w3,
              const float* __restrict__ w4, short* __restrict__ t2t) {
  __shared__ float w3s[20][256];   // 20 KB
  __shared__ float g1s[64][36];    // 9 KB (padded)
  __shared__ float z1s[64][260];   // 66.6 KB (padded)
  __shared__ float bufB[64][132];  // 33.8 KB: w4 k-tile, then t2 bounce
  const int tid = threadIdx.x;
  const int m0  = blockIdx.x * 64;

  for (int j = tid; j < 20 * 256; j += 256) w3s[j >> 8][j & 255] = w3[j];
  {
    const int r = tid >> 2, c0 = (tid & 3) * 8;
    f32x4 s0 = {0.f, 0.f, 0.f, 0.f}, s1 = {0.f, 0.f, 0.f, 0.f};
#pragma unroll
    for (int i = 0; i < 8; ++i) {
      const float* p = P + (size_t)i * MPAD * 32 + (size_t)(m0 + r) * 32 + c0;
      s0 += *(const f32x4*)p;
      s1 += *(const f32x4*)(p + 4);
    }
    *(f32x4*)&g1s[r][c0] = s0;
    *(f32x4*)&g1s[r][c0 + 4] = s1;
  }
  __syncthreads();
  {  // z1 = tanh(g1 @ w3): thread = (row r, 64-col strip)
    const int r = tid >> 2, c0 = (tid & 3) * 64;
    float a[20];
#pragma unroll
    for (int k = 0; k < 20; ++k) a[k] = g1s[r][k];
    for (int c = 0; c < 64; c += 4) {
      f32x4 s = {0.f, 0.f, 0.f, 0.f};
#pragma unroll
      for (int k = 0; k < 20; ++k) s += a[k] * *(const f32x4*)&w3s[k][c0 + c];
      z1s[r][c0 + c + 0] = tanhf(s[0]); z1s[r][c0 + c + 1] = tanhf(s[1]);
      z1s[r][c0 + c + 2] = tanhf(s[2]); z1s[r][c0 + c + 3] = tanhf(s[3]);
    }
  }
  // t2 = z1 @ w4 (K=256 in 4 tiles of 64)
  const int r = tid >> 2, c0 = (tid & 3) * 32;
  float acc[32];
#pragma unroll
  for (int j = 0; j < 32; ++j) acc[j] = 0.f;
  for (int kt = 0; kt < 4; ++kt) {
    __syncthreads();
    {
      const int lr = tid >> 2, lc = (tid & 3) * 32;
#pragma unroll
      for (int j = 0; j < 32; j += 4)
        *(f32x4*)&bufB[lr][lc + j] =
            *(const f32x4*)(w4 + (size_t)(kt * 64 + lr) * 128 + lc + j);
    }
    __syncthreads();
    for (int k = 0; k < 64; ++k) {
      const float a = z1s[r][kt * 64 + k];
#pragma unroll
      for (int j = 0; j < 32; j += 4) {
        f32x4 w = *(const f32x4*)&bufB[k][c0 + j];
        acc[j + 0] += a * w[0]; acc[j + 1] += a * w[1];
        acc[j + 2] += a * w[2]; acc[j + 3] += a * w[3];
      }
    }
  }
  __syncthreads();
#pragma unroll
  for (int j = 0; j < 32; j += 4) *(f32x4*)&bufB[r][c0 + j] = *(const f32x4*)&acc[j];
  __syncthreads();
  {  // transposed bf16 store: row n of t2t, 32-col m-segment
    const int n = tid >> 1, seg = (tid & 1) * 32;
    unsigned short h[32] __attribute__((aligned(16)));
#pragma unroll
    for (int i = 0; i < 32; ++i) h[i] = f2bf(bufB[seg + i][n]);
    uint4* dst = (uint4*)(t2t + (size_t)n * MP + m0 + seg);
    dst[0] = *(const uint4*)&h[0];  dst[1] = *(const uint4*)&h[8];
    dst[2] = *(const uint4*)&h[16]; dst[3] = *(const uint4*)&h[24];
  }
}

// ---------------------------------------------------------------------------
// reduce128h: g3 = sum(P partials) [f32 + bf16], h = g3 @ Mm -> hb bf16.
// Rows >= NROWS come out zero automatically (P partials are zero there).
// ---------------------------------------------------------------------------
__global__ __launch_bounds__(256)
void reduce128h(const float* __restrict__ P, const float* __restrict__ Mm,
                float* __restrict__ g3, short* __restrict__ g3b,
                short* __restrict__ hb) {
  __shared__ float MmS[128 * 128];  // 64 KB
  __shared__ float g3t[64][132];    // 33.8 KB (padded)
  const int tid = threadIdx.x;
  const int m0  = blockIdx.x * 64;

  for (int j = tid; j < 128 * 128; j += 256) MmS[j] = Mm[j];
  const int r = tid >> 2, c0 = (tid & 3) * 32;
  {
    const int gr = m0 + r;
    for (int c = 0; c < 32; c += 4) {
      f32x4 s = {0.f, 0.f, 0.f, 0.f};
#pragma unroll
      for (int i = 0; i < 8; ++i)
        s += *(const f32x4*)(P + (size_t)i * MPAD * 128 + (size_t)gr * 128 + c0 + c);
      *(f32x4*)&g3t[r][c0 + c] = s;
      *(f32x4*)(g3 + (size_t)gr * 128 + c0 + c) = s;
      short4 sb;
      sb.x = (short)f2bf(s[0]); sb.y = (short)f2bf(s[1]);
      sb.z = (short)f2bf(s[2]); sb.w = (short)f2bf(s[3]);
      *(short4*)(g3b + (size_t)gr * 128 + c0 + c) = sb;
    }
  }
  __syncthreads();
  float acc[32];
#pragma unroll
  for (int j = 0; j < 32; ++j) acc[j] = 0.f;
  for (int k = 0; k < 128; ++k) {
    const float a = g3t[r][k];
#pragma unroll
    for (int j = 0; j < 32; j += 4) {
      const float* mv = &MmS[k * 128 + c0 + j];
      acc[j + 0] += a * mv[0]; acc[j + 1] += a * mv[1];
      acc[j + 2] += a * mv[2]; acc[j + 3] += a * mv[3];
    }
  }
  unsigned short h[32] __attribute__((aligned(16)));
#pragma unroll
  for (int j = 0; j < 32; ++j) h[j] = f2bf(acc[j]);
  uint4* dst = (uint4*)(hb + (size_t)(m0 + r) * 128 + c0);
  dst[0] = *(const uint4*)&h[0]; dst[1] = *(const uint4*)&h[8];
  dst[2] = *(const uint4*)&h[16]; dst[3] = *(const uint4*)&h[24];
}

// ---------------------------------------------------------------------------
// f32 tiled GEMMs for small ops (z_hat, Mm). 64x64 tile, 4x4/thread.
// ---------------------------------------------------------------------------
#define TK 16
#define TM 64
#define TN 64

template <int ACT>
__global__ __launch_bounds__(256)
void gemm_nn_f32(const float* __restrict__ A, int lda,
                 const float* __restrict__ B, int ldb,
                 float* __restrict__ C, int ldc, int M, int N, int K) {
  __shared__ float Asm[TK][TM + 4];
  __shared__ float Bsm[TK][TN + 4];
  const int tid = threadIdx.x;
  const int tx = tid & 15, ty = tid >> 4;
  const int row0 = blockIdx.y * TM, col0 = blockIdx.x * TN;
  const int a_m = tid >> 2, a_k = (tid & 3) << 2;
  const int b_k = tid >> 4, b_n = (tid & 15) << 2;
  float acc[4][4] = {};
  const int ntile = (K + TK - 1) / TK;

  auto ld_a = [&](int k0) {
    float4 v = make_float4(0.f, 0.f, 0.f, 0.f);
    int r = row0 + a_m, k = k0 + a_k;
    if (r < M && k < K) v = *(const float4*)(A + (size_t)r * lda + k);
    return v;
  };
  auto ld_b = [&](int k0) {
    float4 v = make_float4(0.f, 0.f, 0.f, 0.f);
    int k = k0 + b_k, c = col0 + b_n;
    if (k < K && c + 3 < N) v = *(const float4*)(B + (size_t)k * ldb + c);
    return v;
  };

  float4 pa = ld_a(0), pb = ld_b(0);
  for (int t = 0; t < ntile; ++t) {
    __syncthreads();
    Asm[a_k + 0][a_m] = pa.x; Asm[a_k + 1][a_m] = pa.y;
    Asm[a_k + 2][a_m] = pa.z; Asm[a_k + 3][a_m] = pa.w;
    *(float4*)&Bsm[b_k][b_n] = pb;
    __syncthreads();
    if (t + 1 < ntile) { pa = ld_a((t + 1) * TK); pb = ld_b((t + 1) * TK); }
#pragma unroll
    for (int kk = 0; kk < TK; ++kk) {
      float4 a = *(const float4*)&Asm[kk][ty << 2];
      float4 b = *(const float4*)&Bsm[kk][tx << 2];
      float av[4] = {a.x, a.y, a.z, a.w};
      float bv[4] = {b.x, b.y, b.z, b.w};
#pragma unroll
      for (int i = 0; i < 4; ++i)
#pragma unroll
        for (int j = 0; j < 4; ++j) acc[i][j] += av[i] * bv[j];
    }
  }
#pragma unroll
  for (int i = 0; i < 4; ++i) {
    int r = row0 + (ty << 2) + i;
    if (r >= M) continue;
#pragma unroll
    for (int j = 0; j < 4; ++j) {
      int c = col0 + (tx << 2) + j;
      if (c >= N) continue;
      float v = acc[i][j];
      if (ACT == 1) v = tanhf(v);
      C[(size_t)r * ldc + c] = v;
    }
  }
}

__global__ __launch_bounds__(256)
void gemm_nt_f32(const float* __restrict__ A, int lda,
                 const float* __restrict__ B, int ldb,
                 float* __restrict__ C, int ldc, int M, int N, int K) {
  __shared__ float Asm[TK][TM + 4];
  __shared__ float Bsm[TK][TN + 4];
  const int tid = threadIdx.x;
  const int tx = tid & 15, ty = tid >> 4;
  const int row0 = blockIdx.y * TM, col0 = blockIdx.x * TN;
  const int a_m = tid >> 2, a_k = (tid & 3) << 2;
  const int b_n = tid >> 2, b_k = (tid & 3) << 2;
  float acc[4][4] = {};
  const int ntile = (K + TK - 1) / TK;

  auto ld_a = [&](int k0) {
    float4 v = make_float4(0.f, 0.f, 0.f, 0.f);
    int r = row0 + a_m, k = k0 + a_k;
    if (r < M && k + 3 < K) v = *(const float4*)(A + (size_t)r * lda + k);
    return v;
  };
  auto ld_b = [&](int k0) {
    float4 v = make_float4(0.f, 0.f, 0.f, 0.f);
    int c = col0 + b_n, k = k0 + b_k;
    if (c < N && k + 3 < K) v = *(const float4*)(B + (size_t)c * ldb + k);
    return v;
  };

  float4 pa = ld_a(0), pb = ld_b(0);
  for (int t = 0; t < ntile; ++t) {
    __syncthreads();
    Asm[a_k + 0][a_m] = pa.x; Asm[a_k + 1][a_m] = pa.y;
    Asm[a_k + 2][a_m] = pa.z; Asm[a_k + 3][a_m] = pa.w;
    Bsm[b_k + 0][b_n] = pb.x; Bsm[b_k + 1][b_n] = pb.y;
    Bsm[b_k + 2][b_n] = pb.z; Bsm[b_k + 3][b_n] = pb.w;
    __syncthreads();
    if (t + 1 < ntile) { pa = ld_a((t + 1) * TK); pb = ld_b((t + 1) * TK); }
#pragma unroll
    for (int kk = 0; kk < TK; ++kk) {
      float4 a = *(const float4*)&Asm[kk][ty << 2];
      float4 b = *(const float4*)&Bsm[kk][tx << 2];
      float av[4] = {a.x, a.y, a.z, a.w};
      float bv[4] = {b.x, b.y, b.z, b.w};
#pragma unroll
      for (int i = 0; i < 4; ++i)
#pragma unroll
        for (int j = 0; j < 4; ++j) acc[i][j] += av[i] * bv[j];
    }
  }
#pragma unroll
  for (int i = 0; i < 4; ++i) {
    int r = row0 + (ty << 2) + i;
    if (r >= M) continue;
#pragma unroll
    for (int j = 0; j < 4; ++j) {
      int c = col0 + (tx << 2) + j;
      if (c >= N) continue;
      C[(size_t)r * ldc + c] = acc[i][j];
    }
  }
}

// --------------------------- helper kernels --------------------------------

__global__ void tr_zigae(const float* __restrict__ z, short* __restrict__ zt) {
  int m = blockIdx.x * 256 + threadIdx.x;
  int n = blockIdx.y;
  if (m >= MP) return;
  float v = (n < 20 && m < NROWS) ? z[(size_t)m * 20 + n] : 0.f;
  zt[(size_t)n * MP + m] = f2bf(v);
}

// Fused: sum 8 partials -> tanh -> transposed bf16 [128][MP] (zero m>=NROWS)
__global__ __launch_bounds__(256)
void reduce_tr(const float* __restrict__ P, short* __restrict__ z2t) {
  __shared__ float T[128][33];
  const int tid = threadIdx.x;
  const int m0 = blockIdx.x * 32;
  const int mr = tid >> 5;
  const int n0 = (tid & 31) * 4;
#pragma unroll
  for (int g = 0; g < 4; ++g) {
    const int mm = g * 8 + mr;
    const int m = m0 + mm;
    f32x4 sAcc = (f32x4){0.f, 0.f, 0.f, 0.f};
#pragma unroll
    for (int i = 0; i < 8; ++i)
      sAcc += *(const f32x4*)(P + (size_t)i * MPAD * 128 + (size_t)m * 128 + n0);
    if (m < NROWS) {
      T[n0 + 0][mm] = tanhf(sAcc[0]); T[n0 + 1][mm] = tanhf(sAcc[1]);
      T[n0 + 2][mm] = tanhf(sAcc[2]); T[n0 + 3][mm] = tanhf(sAcc[3]);
    } else {
      T[n0 + 0][mm] = 0.f; T[n0 + 1][mm] = 0.f;
      T[n0 + 2][mm] = 0.f; T[n0 + 3][mm] = 0.f;
    }
  }
  __syncthreads();
  const int n = tid >> 1, mh = (tid & 1) * 16;
  unsigned short h[16] __attribute__((aligned(16)));
#pragma unroll
  for (int j = 0; j < 16; ++j) h[j] = f2bf(T[n][mh + j]);
  *(uint4*)(z2t + (size_t)n * MP + m0 + mh)     = *(const uint4*)&h[0];
  *(uint4*)(z2t + (size_t)n * MP + m0 + mh + 8) = *(const uint4*)&h[8];
}

// ---------------------------------------------------------------------------
extern "C" void kernel_launch(void* const* d_in, const int* in_sizes, int n_in,
                              void* d_out, int out_size, void* d_ws, size_t ws_size,
                              hipStream_t stream) {
  const float* z_igae = (const float*)d_in[0];
  const float* adj    = (const float*)d_in[1];
  const float* w3     = (const float*)d_in[2];
  const float* w4     = (const float*)d_in[3];
  const float* w5     = (const float*)d_in[4];

  const int M = NROWS, D2 = 256, D3 = 128, NI = 500;
  const int S = 8, KC = MP / 64;  // 157 BK-chunks

  float* z_hat   = (float*)d_out;                      // [M, NI]
  float* out_adj = (float*)d_out + (size_t)M * NI;     // [M, M] = 400 MB

  // scratch inside out_adj region (fully consumed before recon writes it)
  char* oa = (char*)out_adj;
  short* adjb = (short*)oa;                            // [MPAD][MP] bf16, 203.2 MB
  float* P    = (float*)(oa + 204ll * 1024 * 1024);    // 8*MPAD*128*4 = 41.4 MB
  char*  sc   = oa + 248ll * 1024 * 1024;
  short* t2t  = (short*)(sc);                          // [128][MP]  2.6 MB
  short* z2t  = (short*)(sc + 3ll * 1024 * 1024);      // [128][MP]  2.6 MB
  short* zt   = (short*)(sc + 6ll * 1024 * 1024);      // [32][MP]   0.65 MB
  float* Mm   = (float*)(sc + 7ll * 1024 * 1024);      // [128][128] 64 KB
  float* g3   = (float*)(sc + 8ll * 1024 * 1024);      // [MPAD][128] 5.2 MB

  // recon inputs in d_ws (must survive until recon writes out_adj)
  short* hb  = (short*)d_ws;                           // [MPAD][128] 2.59 MB
  short* g3b = (short*)d_ws + (size_t)MPAD * 128;      // [MPAD][128] 2.59 MB

  dim3 blk(256);

  // 1. Mm = w5 @ w5^T (needed by reduce128h)
  gemm_nt_f32<<<dim3(2, 2), blk, 0, stream>>>(w5, NI, w5, NI, Mm, D3, D3, D3, NI);
  // 2. z_igae^T -> bf16 [32][MP]
  tr_zigae<<<dim3(40, 32), blk, 0, stream>>>(z_igae, zt);
  // 3. fused: adj f32 -> adjb bf16 AND g1 partials (rows to MPAD)
  gemm1_fused<<<dim3(1, 158, S), blk, 0, stream>>>(adj, zt, adjb, P, KC, S);
  // 4. midchain: g1 -> z1 -> t2 -> t2t
  midchain<<<dim3(157), blk, 0, stream>>>(P, w3, w4, t2t);
  // 5. z2 partials = adj @ t2 (BM=128, all-resident), then reduce+tanh+tr
  gemm_adj<<<dim3(1, 79, S), blk, 0, stream>>>(adjb, t2t, P, KC, S);
  reduce_tr<<<dim3(314), blk, 0, stream>>>(P, z2t);
  // 6. g3 partials = adj @ z2
  gemm_adj<<<dim3(1, 79, S), blk, 0, stream>>>(adjb, z2t, P, KC, S);
  // 7. g3 (f32+bf16) + h = g3@Mm (bf16), rows padded to MPAD
  reduce128h<<<dim3(158), blk, 0, stream>>>(P, Mm, g3, g3b, hb);
  // 8. z_hat = g3 @ w5 -> out0
  gemm_nn_f32<0><<<dim3(8, 157), blk, 0, stream>>>(g3, D3, w5, NI, z_hat, NI, M, NI, D3);
  // 9. out1 = sigmoid(h @ g3^T) — overwrites all scratch in out_adj
  gemm_recon<<<dim3(79, 79), blk, 0, stream>>>(hb, g3b, out_adj);
}